// Round 1
// baseline (285.112 us; speedup 1.0000x reference)
//
#include <hip/hip_runtime.h>
#include <math.h>

// CRDLoss on MI355X.
// Phase 0: convert W_s/W_t -> fp16 in ws (1 MB, L2-resident thereafter).
// Phase 1: embed (GEMM 8192x2048x128 + bias + L2 norm) -> fp16 embeddings.
//          R8: BK=128 (16 iters), 2-tile-ahead register prefetch, raw
//          s_barrier + lgkmcnt(0) (keeps global loads in flight across the
//          barrier -- __syncthreads would drain vmcnt(0), the m97 stall).
//          LDS exactly 80 KB -> 2 blocks/CU (grid-limited occupancy).
// Phase 2: 8192x8192 similarity via f16 MFMA, fused exp/log epilogue.
// Phase 3: reduce 4096 partials -> out[0] = -(sum)/B.

typedef _Float16 half_t;
typedef half_t halfx4 __attribute__((ext_vector_type(4)));
typedef half_t halfx8 __attribute__((ext_vector_type(8)));
typedef float f32x4 __attribute__((ext_vector_type(4)));

#define B_TOT   8192
#define K_EMB   2048
#define F_DIM   128
#define INV_T   14.285714285714286f   // 1/0.07
#define EPS_C   0.97f
#define LOG_EPS (-0.030459207485f)    // ln(0.97)

// ---------------------------------------------------------------------------
// W fp32 -> fp16.  grid = (256, 2); block = 256; one float4 per thread.
// ---------------------------------------------------------------------------
__global__ __launch_bounds__(256) void cvt_w_kernel(
    const float* __restrict__ Ws, const float* __restrict__ Wt,
    half_t* __restrict__ Ws16, half_t* __restrict__ Wt16)
{
    const float* src = blockIdx.y ? Wt : Ws;
    half_t* dst = blockIdx.y ? Wt16 : Ws16;
    int pos4 = blockIdx.x * 256 + threadIdx.x;      // 0..65535
    float4 v = *(const float4*)(src + (size_t)pos4 * 4);
    halfx4 h4 = {(half_t)v.x, (half_t)v.y, (half_t)v.z, (half_t)v.w};
    *(halfx4*)(dst + (size_t)pos4 * 4) = h4;
}

// ---------------------------------------------------------------------------
// Embed: 32-row tile x all 128 cols, BK=128, double-buffered LDS,
// 2-tile-ahead register prefetch.
// grid = (256, 2); block = 256 (4 waves: wm=w&1 row-halves, wn=w>>1 col-halves).
// LDS layout (uint4 units): [As0 512][As1 512][Bs0 2048][Bs1 2048] = 80 KB.
// Row = 16 uint4 (128 halves), slot XOR-swizzled by (row & 15).
// ---------------------------------------------------------------------------
__device__ __forceinline__ void cvst(uint4* dst, float4 x, float4 y)
{
    halfx8 h = {(half_t)x.x, (half_t)x.y, (half_t)x.z, (half_t)x.w,
                (half_t)y.x, (half_t)y.y, (half_t)y.z, (half_t)y.w};
    *(halfx8*)dst = h;
}

__global__ __launch_bounds__(256, 2) void embed_kernel(
    const float* __restrict__ Xs, const float* __restrict__ Xt,
    const half_t* __restrict__ Ws16, const half_t* __restrict__ Wt16,
    const float* __restrict__ bs, const float* __restrict__ bt,
    half_t* __restrict__ outs, half_t* __restrict__ outt)
{
    const float* X; const half_t* W16; const float* bias; half_t* out;
    if (blockIdx.y == 0) { X = Xs; W16 = Ws16; bias = bs; out = outs; }
    else                 { X = Xt; W16 = Wt16; bias = bt; out = outt; }

    __shared__ uint4 smem[5120];   // exactly 80 KB -> 2 blocks/CU

    const int tid  = threadIdx.x;
    const int r0   = blockIdx.x * 32;
    const int lane = tid & 63;
    const int w    = tid >> 6;
    const int wm   = w & 1, wn = w >> 1;     // rows 16*wm, cols 64*wn
    const int l16  = lane & 15, lhi = lane >> 4;

    // bias into registers early (L2-hot, fully hidden under the K loop)
    float bv[4];
#pragma unroll
    for (int in = 0; in < 4; ++in) bv[in] = bias[wn * 64 + in * 16 + l16];

    // --- staging coordinates ------------------------------------------------
    // A: 32 rows x 16 uint4/row; each thread owns 2 chunks (rows ar0, ar0+16).
    const int ar0 = tid >> 4;                 // 0..15
    const int ac  = tid & 15;                 // slot 0..15
    const int axr = ac ^ ar0;                 // swizzled slot ((row&15) == ar0)
    const int adst0 = ar0 * 16 + axr;         // chunk 0 dst (uint4 idx in As)
    const int adst1 = adst0 + 256;            // chunk 1 dst (row + 16)
    const float* aptr0 = X + (size_t)(r0 + ar0) * K_EMB + ac * 8;
    const float* aptr1 = aptr0 + (size_t)16 * K_EMB;
    // B: 128 rows x 16 uint4/row; 8 chunks/thread (rows ar0 + i*16).
    // (brow & 15) == ar0 for all i -> same swizzled slot axr; dst = adst0+i*256.
    const half_t* bptr = W16 + (size_t)ar0 * K_EMB + ac * 8;

    f32x4 acc[4];
#pragma unroll
    for (int in = 0; in < 4; ++in) acc[in] = f32x4{0.f, 0.f, 0.f, 0.f};

    float4 aR0[4], aR1[4];
    uint4  bR0[8], bR1[8];

#define LOADT(aR, bR, KB) do {                                                 \
        aR[0] = *(const float4*)(aptr0 + (KB));                                \
        aR[1] = *(const float4*)(aptr0 + (KB) + 4);                            \
        aR[2] = *(const float4*)(aptr1 + (KB));                                \
        aR[3] = *(const float4*)(aptr1 + (KB) + 4);                            \
        _Pragma("unroll")                                                      \
        for (int i = 0; i < 8; ++i)                                            \
            bR[i] = *(const uint4*)(bptr + (KB) + (size_t)i * 16 * K_EMB);     \
    } while (0)

#define STORET(aR, bR, BUF) do {                                               \
        cvst(&smem[(BUF) * 512 + adst0], aR[0], aR[1]);                        \
        cvst(&smem[(BUF) * 512 + adst1], aR[2], aR[3]);                        \
        _Pragma("unroll")                                                      \
        for (int i = 0; i < 8; ++i)                                            \
            smem[1024 + (BUF) * 2048 + adst0 + i * 256] = bR[i];               \
    } while (0)

#define COMPUTE(BUF) do {                                                      \
        _Pragma("unroll")                                                      \
        for (int kk = 0; kk < 4; ++kk) {                                       \
            const int sl = (kk * 4 + lhi) ^ l16;                               \
            halfx8 afrag = *(const halfx8*)&smem[(BUF) * 512 +                 \
                                                 (wm * 16 + l16) * 16 + sl];   \
            _Pragma("unroll")                                                  \
            for (int in = 0; in < 4; ++in) {                                   \
                halfx8 bfrag = *(const halfx8*)&smem[1024 + (BUF) * 2048 +     \
                                     (wn * 64 + in * 16 + l16) * 16 + sl];     \
                acc[in] = __builtin_amdgcn_mfma_f32_16x16x32_f16(              \
                    afrag, bfrag, acc[in], 0, 0, 0);                           \
            }                                                                  \
        }                                                                      \
    } while (0)

    // lgkmcnt(0) only: ds_writes visible, global loads stay in flight
#define BARRIER() do {                                                         \
        asm volatile("s_waitcnt lgkmcnt(0)" ::: "memory");                     \
        __builtin_amdgcn_s_barrier();                                          \
    } while (0)

    // prologue: T0 -> LDS0; T1 -> regs
    LOADT(aR0, bR0, 0);
    STORET(aR0, bR0, 0);
    LOADT(aR1, bR1, 128);
    BARRIER();

    // steady state: invariant at itp: LDS0 = T(itp), regs1 = T(itp+1)
    for (int itp = 0; itp < 14; itp += 2) {
        LOADT(aR0, bR0, (itp + 2) * 128);
        COMPUTE(0);
        STORET(aR1, bR1, 1);
        BARRIER();
        LOADT(aR1, bR1, (itp + 3) * 128);
        COMPUTE(1);
        STORET(aR0, bR0, 0);
        BARRIER();
    }
    // tail: LDS0 = T14, regs1 = T15
    COMPUTE(0);
    STORET(aR1, bR1, 1);
    BARRIER();
    COMPUTE(1);

#undef LOADT
#undef STORET
#undef COMPUTE
#undef BARRIER

    // epilogue: +bias, row sum-of-squares, normalize, fp16 store.
    // Reduction scratch aliases the As0 region (no longer read; disjoint from
    // the LDS1 region other waves may still be reading in COMPUTE(1)).
    float* redS = (float*)smem;          // [32][2]
    float* invS = ((float*)smem) + 64;   // [32]

    float hh[4][4];
    float psum[4];
#pragma unroll
    for (int reg = 0; reg < 4; ++reg) {
        float p = 0.f;
#pragma unroll
        for (int in = 0; in < 4; ++in) {
            float v = acc[in][reg] + bv[in];
            hh[in][reg] = v;
            p += v * v;
        }
        p += __shfl_xor(p, 1);
        p += __shfl_xor(p, 2);
        p += __shfl_xor(p, 4);
        p += __shfl_xor(p, 8);
        psum[reg] = p;
    }
    if (l16 == 0)
#pragma unroll
        for (int reg = 0; reg < 4; ++reg)
            redS[(wm * 16 + lhi * 4 + reg) * 2 + wn] = psum[reg];
    __syncthreads();
    if (tid < 32) invS[tid] = rsqrtf(redS[tid * 2] + redS[tid * 2 + 1]);
    __syncthreads();

#pragma unroll
    for (int in = 0; in < 4; ++in)
#pragma unroll
        for (int reg = 0; reg < 4; ++reg) {
            int row = wm * 16 + lhi * 4 + reg;
            int col = wn * 64 + in * 16 + l16;
            out[(size_t)(r0 + row) * F_DIM + col] = (half_t)(hh[in][reg] * invS[row]);
        }
}

// ---------------------------------------------------------------------------
// Loss: 128x128 tile of fs·ft^T, K=128 in two 64-wide LDS chunks (33 KB LDS).
// grid = (64, 64); block = 256.  (unchanged)
// ---------------------------------------------------------------------------
__global__ __launch_bounds__(256) void loss_kernel(
    const half_t* __restrict__ FS, const half_t* __restrict__ FT,
    const int* __restrict__ y, double* __restrict__ partials)
{
    __shared__ uint4 As4[128 * 8];   // 16 KB
    __shared__ uint4 Bs4[128 * 8];   // 16 KB
    __shared__ int   yrl[128], ycl[128];
    __shared__ float wsum[4];

    const int tid = threadIdx.x;
    const int i0  = blockIdx.x * 128;
    const int j0  = blockIdx.y * 128;

    if (tid < 128) yrl[tid] = y[i0 + tid];
    else           ycl[tid - 128] = y[j0 + tid - 128];

    const int lane = tid & 63;
    const int w    = tid >> 6;
    const int wm   = w >> 1, wn = w & 1;
    const int l16  = lane & 15, lhi = lane >> 4;

#pragma unroll
    for (int i = 0; i < 4; ++i) {
        int f = tid + i * 256;
        int row = f >> 3, c = f & 7;
        As4[row * 8 + (c ^ (row & 7))] = *(const uint4*)(FS + (size_t)(i0 + row) * F_DIM + c * 8);
    }
#pragma unroll
    for (int i = 0; i < 4; ++i) {
        int f = tid + i * 256;
        int row = f >> 3, c = f & 7;
        Bs4[row * 8 + (c ^ (row & 7))] = *(const uint4*)(FT + (size_t)(j0 + row) * F_DIM + c * 8);
    }
    __syncthreads();

    f32x4 acc[4][4];
    for (int im = 0; im < 4; ++im)
        for (int in = 0; in < 4; ++in)
            acc[im][in] = f32x4{0.f, 0.f, 0.f, 0.f};

    for (int kc = 0; kc < 2; ++kc) {
#pragma unroll
        for (int kk = 0; kk < 2; ++kk) {
            halfx8 a[4], b[4];
#pragma unroll
            for (int im = 0; im < 4; ++im) {
                int r = wm * 64 + im * 16 + l16;
                a[im] = *(const halfx8*)&As4[r * 8 + ((kk * 4 + lhi) ^ (r & 7))];
            }
#pragma unroll
            for (int in = 0; in < 4; ++in) {
                int r = wn * 64 + in * 16 + l16;
                b[in] = *(const halfx8*)&Bs4[r * 8 + ((kk * 4 + lhi) ^ (r & 7))];
            }
#pragma unroll
            for (int im = 0; im < 4; ++im)
#pragma unroll
                for (int in = 0; in < 4; ++in)
                    acc[im][in] = __builtin_amdgcn_mfma_f32_16x16x32_f16(
                        a[im], b[in], acc[im][in], 0, 0, 0);
        }
        if (kc == 0) {
            __syncthreads();
#pragma unroll
            for (int i = 0; i < 4; ++i) {
                int f = tid + i * 256;
                int row = f >> 3, c = f & 7;
                As4[row * 8 + (c ^ (row & 7))] =
                    *(const uint4*)(FS + (size_t)(i0 + row) * F_DIM + 64 + c * 8);
            }
#pragma unroll
            for (int i = 0; i < 4; ++i) {
                int f = tid + i * 256;
                int row = f >> 3, c = f & 7;
                Bs4[row * 8 + (c ^ (row & 7))] =
                    *(const uint4*)(FT + (size_t)(j0 + row) * F_DIM + 64 + c * 8);
            }
            __syncthreads();
        }
    }

    float local = 0.f;
    for (int im = 0; im < 4; ++im) {
        for (int reg = 0; reg < 4; ++reg) {
            int il = wm * 64 + im * 16 + lhi * 4 + reg;
            int yi = yrl[il];
            int gi = i0 + il;
            for (int in = 0; in < 4; ++in) {
                int jl = wn * 64 + in * 16 + l16;
                float s  = acc[im][in][reg];
                float sT = s * INV_T;
                float e  = __expf(sT);
                float l  = __logf(e + EPS_C);
                float term = (yi == ycl[jl]) ? (sT - l) : (LOG_EPS - l);
                if (gi != (j0 + jl)) local += term;
            }
        }
    }
    for (int m = 1; m < 64; m <<= 1) local += __shfl_xor(local, m);
    if (lane == 0) wsum[w] = local;
    __syncthreads();
    if (tid == 0)
        partials[blockIdx.y * gridDim.x + blockIdx.x] =
            ((double)wsum[0] + (double)wsum[1]) + ((double)wsum[2] + (double)wsum[3]);
}

// ---------------------------------------------------------------------------
__global__ __launch_bounds__(256) void finalize_kernel(
    const double* __restrict__ partials, float* __restrict__ out)
{
    __shared__ double sh[4];
    double loc = 0.0;
    for (int i = threadIdx.x; i < 4096; i += 256) loc += partials[i];
    for (int m = 1; m < 64; m <<= 1) loc += __shfl_xor(loc, m);
    int lane = threadIdx.x & 63, w = threadIdx.x >> 6;
    if (lane == 0) sh[w] = loc;
    __syncthreads();
    if (threadIdx.x == 0)
        out[0] = (float)(-(sh[0] + sh[1] + sh[2] + sh[3]) / (double)B_TOT);
}

// ---------------------------------------------------------------------------
extern "C" void kernel_launch(void* const* d_in, const int* in_sizes, int n_in,
                              void* d_out, int out_size, void* d_ws, size_t ws_size,
                              hipStream_t stream)
{
    // ws layout: [partials 32KB | pad->64KB | fs 2MB | ft 2MB | Ws16 512KB | Wt16 512KB]
    const size_t WS_NEEDED = (64 << 10) + (4 << 20) + (1 << 20);
    if (ws_size < WS_NEEDED) return;   // readable failure instead of OOB fault

    const float* f_s = (const float*)d_in[0];
    const float* f_t = (const float*)d_in[1];
    const int*   y   = (const int*)d_in[2];
    const float* W_s = (const float*)d_in[3];
    const float* b_s = (const float*)d_in[4];
    const float* W_t = (const float*)d_in[5];
    const float* b_t = (const float*)d_in[6];
    float* out = (float*)d_out;

    char* ws = (char*)d_ws;
    double* partials = (double*)ws;                               // 32 KB
    half_t* fs   = (half_t*)(ws + (64 << 10));                    // 2 MB
    half_t* ft   = (half_t*)(ws + (64 << 10) + (2 << 20));        // 2 MB
    half_t* Ws16 = (half_t*)(ws + (64 << 10) + (4 << 20));        // 512 KB
    half_t* Wt16 = (half_t*)(ws + (64 << 10) + (4 << 20) + (512 << 10));

    cvt_w_kernel<<<dim3(256, 2), 256, 0, stream>>>(W_s, W_t, Ws16, Wt16);
    embed_kernel<<<dim3(256, 2), 256, 0, stream>>>(f_s, f_t, Ws16, Wt16, b_s, b_t, fs, ft);
    loss_kernel<<<dim3(64, 64), 256, 0, stream>>>(fs, ft, y, partials);
    finalize_kernel<<<1, 256, 0, stream>>>(partials, out);
    (void)in_sizes; (void)n_in; (void)out_size;
}

// Round 2
// 214.200 us; speedup vs baseline: 1.3311x; 1.3311x over previous
//
#include <hip/hip_runtime.h>
#include <math.h>

// CRDLoss on MI355X.
// Phase 0: convert W_s/W_t -> fp16 in ws (1 MB, L2-resident thereafter).
// Phase 1: embed (GEMM 8192x2048x128 + bias + L2 norm) -> fp16 embeddings.
//          R9: BK=128, double-buffered 80KB LDS, XOR-swizzled (R8: conflicts=0).
//          B staged via global_load_lds width=16 (0 data VGPRs; pre-swizzled
//          per-lane global source, linear LDS dest).  A reg-staged 2 tiles
//          ahead (16 VGPRs only -- R8's 96-VGPR reg-prefetch spilled: 236MB
//          scratch writes).  Counted vmcnt(4), never 0 in steady loop; raw
//          s_barrier keeps prefetch in flight across barriers (T3+T4).
// Phase 2: 8192x8192 similarity via f16 MFMA, fused exp/log epilogue.
// Phase 3: reduce 4096 partials -> out[0] = -(sum)/B.

typedef _Float16 half_t;
typedef half_t halfx4 __attribute__((ext_vector_type(4)));
typedef half_t halfx8 __attribute__((ext_vector_type(8)));
typedef float f32x4 __attribute__((ext_vector_type(4)));

#define B_TOT   8192
#define K_EMB   2048
#define F_DIM   128
#define INV_T   14.285714285714286f   // 1/0.07
#define EPS_C   0.97f
#define LOG_EPS (-0.030459207485f)    // ln(0.97)

// ---------------------------------------------------------------------------
// W fp32 -> fp16.  grid = (256, 2); block = 256; one float4 per thread.
// ---------------------------------------------------------------------------
__global__ __launch_bounds__(256) void cvt_w_kernel(
    const float* __restrict__ Ws, const float* __restrict__ Wt,
    half_t* __restrict__ Ws16, half_t* __restrict__ Wt16)
{
    const float* src = blockIdx.y ? Wt : Ws;
    half_t* dst = blockIdx.y ? Wt16 : Ws16;
    int pos4 = blockIdx.x * 256 + threadIdx.x;      // 0..65535
    float4 v = *(const float4*)(src + (size_t)pos4 * 4);
    halfx4 h4 = {(half_t)v.x, (half_t)v.y, (half_t)v.z, (half_t)v.w};
    *(halfx4*)(dst + (size_t)pos4 * 4) = h4;
}

// ---------------------------------------------------------------------------
// Embed helpers
// ---------------------------------------------------------------------------
__device__ __forceinline__ void cvst(uint4* dst, float4 x, float4 y)
{
    halfx8 h = {(half_t)x.x, (half_t)x.y, (half_t)x.z, (half_t)x.w,
                (half_t)y.x, (half_t)y.y, (half_t)y.z, (half_t)y.w};
    *(halfx8*)dst = h;
}

__device__ __forceinline__ void gload_lds16(const void* g, void* l)
{
    __builtin_amdgcn_global_load_lds(
        (const __attribute__((address_space(1))) void*)g,
        (__attribute__((address_space(3))) void*)l,
        16, 0, 0);
}

// ---------------------------------------------------------------------------
// Embed: 32-row tile x all 128 cols, BK=128 (16 k-tiles).
// grid = (256, 2); block = 256 (4 waves: wm=w&1 row-halves, wn=w>>1 col-halves).
// LDS (uint4 units): [As0 512][As1 512][Bs0 2048][Bs1 2048] = 80 KB -> 2 blk/CU.
// Row = 16 uint4 (128 halves); slot XOR-swizzled by (row & 15).
// Bs[row][slot] = W[row][(slot^(row&15))*8 ..+7]  (written by gll linear dest
// from pre-swizzled source); As same relation (written by swizzled ds_write).
// ---------------------------------------------------------------------------
__global__ __launch_bounds__(256) void embed_kernel(
    const float* __restrict__ Xs, const float* __restrict__ Xt,
    const half_t* __restrict__ Ws16, const half_t* __restrict__ Wt16,
    const float* __restrict__ bs, const float* __restrict__ bt,
    half_t* __restrict__ outs, half_t* __restrict__ outt)
{
    const float* X; const half_t* W16; const float* bias; half_t* out;
    if (blockIdx.y == 0) { X = Xs; W16 = Ws16; bias = bs; out = outs; }
    else                 { X = Xt; W16 = Wt16; bias = bt; out = outt; }

    __shared__ uint4 smem[5120];   // exactly 80 KB

    const int tid  = threadIdx.x;
    const int r0   = blockIdx.x * 32;
    const int lane = tid & 63;
    const int w    = tid >> 6;
    const int wm   = w & 1, wn = w >> 1;     // rows 16*wm, cols 64*wn
    const int l16  = lane & 15, lhi = lane >> 4;

    // bias into registers early (retired by the prologue drain)
    float bv[4];
#pragma unroll
    for (int in = 0; in < 4; ++in) bv[in] = bias[wn * 64 + in * 16 + l16];

    // --- A staging (reg path): 32 rows x 16 uint4; 2 dest chunks/thread ----
    const int ar0 = tid >> 4;                 // 0..15 (rows ar0, ar0+16)
    const int ac  = tid & 15;                 // source slot
    const int axz = ac ^ ar0;                 // swizzled slot ((row&15)==ar0)
    const float* aptr0 = X + (size_t)(r0 + ar0) * K_EMB + ac * 8;
    const float* aptr1 = aptr0 + (size_t)16 * K_EMB;

    // --- B staging (global_load_lds): wave w owns rows w*32..w*32+31 --------
    // issue i covers rows w*32+i*4..+3; lane l -> row +(l>>4), linear slot l&15.
    // Source column pre-swizzled so linear LDS ends up XOR-swizzled.
    const half_t* bgp[8];
#pragma unroll
    for (int i = 0; i < 8; ++i) {
        int rl = w * 32 + i * 4 + (lane >> 4);
        bgp[i] = W16 + (size_t)rl * K_EMB + (size_t)(((lane & 15) ^ (rl & 15)) * 8);
    }

    f32x4 acc[4];
#pragma unroll
    for (int in = 0; in < 4; ++in) acc[in] = f32x4{0.f, 0.f, 0.f, 0.f};

    float4 aR[4];

#define LOADA(T) do {                                                          \
        aR[0] = *(const float4*)(aptr0 + (size_t)(T) * 128);                   \
        aR[1] = *(const float4*)(aptr0 + (size_t)(T) * 128 + 4);               \
        aR[2] = *(const float4*)(aptr1 + (size_t)(T) * 128);                   \
        aR[3] = *(const float4*)(aptr1 + (size_t)(T) * 128 + 4);               \
    } while (0)

#define CVTA(BUF) do {                                                         \
        cvst(&smem[(BUF) * 512 + ar0 * 16 + axz], aR[0], aR[1]);               \
        cvst(&smem[(BUF) * 512 + ar0 * 16 + 256 + axz], aR[2], aR[3]);         \
    } while (0)

#define BGLL(BUF, T) do {                                                      \
        _Pragma("unroll")                                                      \
        for (int i = 0; i < 8; ++i)                                            \
            gload_lds16(bgp[i] + (size_t)(T) * 128,                            \
                        &smem[1024 + (BUF) * 2048 + w * 512 + i * 64]);        \
    } while (0)

#define COMPUTE(BUF) do {                                                      \
        _Pragma("unroll")                                                      \
        for (int kk = 0; kk < 4; ++kk) {                                       \
            const int sl = (kk * 4 + lhi) ^ l16;                               \
            halfx8 afrag = *(const halfx8*)&smem[(BUF) * 512 +                 \
                                                 (wm * 16 + l16) * 16 + sl];   \
            _Pragma("unroll")                                                  \
            for (int in = 0; in < 4; ++in) {                                   \
                halfx8 bfrag = *(const halfx8*)&smem[1024 + (BUF) * 2048 +     \
                                     (wn * 64 + in * 16 + l16) * 16 + sl];     \
                acc[in] = __builtin_amdgcn_mfma_f32_16x16x32_f16(              \
                    afrag, bfrag, acc[in], 0, 0, 0);                           \
            }                                                                  \
        }                                                                      \
    } while (0)

    // ---- prologue: tile0 -> LDS0 (full drain, once); A(1)/B(1) in flight --
    BGLL(0, 0);
    LOADA(0);
    CVTA(0);            // compiler drains vmcnt for A(0) -> also retires B(0)
    LOADA(1);
    BGLL(1, 1);
    asm volatile("s_waitcnt lgkmcnt(0)" ::: "memory");
    __builtin_amdgcn_s_barrier();

    // ---- steady state: 1 barrier/iter, vmcnt never 0 ----------------------
    // invariant at top of iter t: LDS(t&1)=tile t complete; aR=A(t+1) in
    // flight (4); B(t+1) gll in flight (8) into LDS(buf^1).
#pragma unroll 2
    for (int t = 0; t < 14; ++t) {
        const int buf = t & 1;
        COMPUTE(buf);
        CVTA(buf ^ 1);                 // A(t+1): auto vmcnt(8), keeps B(t+1)
        LOADA(t + 2);                  // A(t+2) issue (4 in flight)
        asm volatile("s_waitcnt vmcnt(4) lgkmcnt(0)" ::: "memory");
        __builtin_amdgcn_s_barrier();  // B(t+1)+A(t+1) in LDS; A(t+2) in flight
        BGLL(buf, t + 2);              // safe: all waves done reading buf
    }
    // t = 14
    COMPUTE(0);
    CVTA(1);                           // A(15)
    asm volatile("s_waitcnt vmcnt(0) lgkmcnt(0)" ::: "memory");
    __builtin_amdgcn_s_barrier();
    // t = 15
    COMPUTE(1);

#undef LOADA
#undef CVTA
#undef BGLL
#undef COMPUTE

    // epilogue: +bias, row sum-of-squares, normalize, fp16 store.
    // Reduction scratch aliases As0 (smem[0..511]); waves still finishing
    // COMPUTE(1) only touch As1/Bs1 regions -- disjoint.
    float* redS = (float*)smem;          // [32][2]
    float* invS = ((float*)smem) + 64;   // [32]

    float hh[4][4];
    float psum[4];
#pragma unroll
    for (int reg = 0; reg < 4; ++reg) {
        float p = 0.f;
#pragma unroll
        for (int in = 0; in < 4; ++in) {
            float v = acc[in][reg] + bv[in];
            hh[in][reg] = v;
            p += v * v;
        }
        p += __shfl_xor(p, 1);
        p += __shfl_xor(p, 2);
        p += __shfl_xor(p, 4);
        p += __shfl_xor(p, 8);
        psum[reg] = p;
    }
    if (l16 == 0)
#pragma unroll
        for (int reg = 0; reg < 4; ++reg)
            redS[(wm * 16 + lhi * 4 + reg) * 2 + wn] = psum[reg];
    __syncthreads();
    if (tid < 32) invS[tid] = rsqrtf(redS[tid * 2] + redS[tid * 2 + 1]);
    __syncthreads();

#pragma unroll
    for (int in = 0; in < 4; ++in)
#pragma unroll
        for (int reg = 0; reg < 4; ++reg) {
            int row = wm * 16 + lhi * 4 + reg;
            int col = wn * 64 + in * 16 + l16;
            out[(size_t)(r0 + row) * F_DIM + col] = (half_t)(hh[in][reg] * invS[row]);
        }
}

// ---------------------------------------------------------------------------
// Loss: 128x128 tile of fs·ft^T, K=128 in two 64-wide LDS chunks (33 KB LDS).
// grid = (64, 64); block = 256.  (unchanged)
// ---------------------------------------------------------------------------
__global__ __launch_bounds__(256) void loss_kernel(
    const half_t* __restrict__ FS, const half_t* __restrict__ FT,
    const int* __restrict__ y, double* __restrict__ partials)
{
    __shared__ uint4 As4[128 * 8];   // 16 KB
    __shared__ uint4 Bs4[128 * 8];   // 16 KB
    __shared__ int   yrl[128], ycl[128];
    __shared__ float wsum[4];

    const int tid = threadIdx.x;
    const int i0  = blockIdx.x * 128;
    const int j0  = blockIdx.y * 128;

    if (tid < 128) yrl[tid] = y[i0 + tid];
    else           ycl[tid - 128] = y[j0 + tid - 128];

    const int lane = tid & 63;
    const int w    = tid >> 6;
    const int wm   = w >> 1, wn = w & 1;
    const int l16  = lane & 15, lhi = lane >> 4;

#pragma unroll
    for (int i = 0; i < 4; ++i) {
        int f = tid + i * 256;
        int row = f >> 3, c = f & 7;
        As4[row * 8 + (c ^ (row & 7))] = *(const uint4*)(FS + (size_t)(i0 + row) * F_DIM + c * 8);
    }
#pragma unroll
    for (int i = 0; i < 4; ++i) {
        int f = tid + i * 256;
        int row = f >> 3, c = f & 7;
        Bs4[row * 8 + (c ^ (row & 7))] = *(const uint4*)(FT + (size_t)(j0 + row) * F_DIM + c * 8);
    }
    __syncthreads();

    f32x4 acc[4][4];
    for (int im = 0; im < 4; ++im)
        for (int in = 0; in < 4; ++in)
            acc[im][in] = f32x4{0.f, 0.f, 0.f, 0.f};

    for (int kc = 0; kc < 2; ++kc) {
#pragma unroll
        for (int kk = 0; kk < 2; ++kk) {
            halfx8 a[4], b[4];
#pragma unroll
            for (int im = 0; im < 4; ++im) {
                int r = wm * 64 + im * 16 + l16;
                a[im] = *(const halfx8*)&As4[r * 8 + ((kk * 4 + lhi) ^ (r & 7))];
            }
#pragma unroll
            for (int in = 0; in < 4; ++in) {
                int r = wn * 64 + in * 16 + l16;
                b[in] = *(const halfx8*)&Bs4[r * 8 + ((kk * 4 + lhi) ^ (r & 7))];
            }
#pragma unroll
            for (int im = 0; im < 4; ++im)
#pragma unroll
                for (int in = 0; in < 4; ++in)
                    acc[im][in] = __builtin_amdgcn_mfma_f32_16x16x32_f16(
                        a[im], b[in], acc[im][in], 0, 0, 0);
        }
        if (kc == 0) {
            __syncthreads();
#pragma unroll
            for (int i = 0; i < 4; ++i) {
                int f = tid + i * 256;
                int row = f >> 3, c = f & 7;
                As4[row * 8 + (c ^ (row & 7))] =
                    *(const uint4*)(FS + (size_t)(i0 + row) * F_DIM + 64 + c * 8);
            }
#pragma unroll
            for (int i = 0; i < 4; ++i) {
                int f = tid + i * 256;
                int row = f >> 3, c = f & 7;
                Bs4[row * 8 + (c ^ (row & 7))] =
                    *(const uint4*)(FT + (size_t)(j0 + row) * F_DIM + 64 + c * 8);
            }
            __syncthreads();
        }
    }

    float local = 0.f;
    for (int im = 0; im < 4; ++im) {
        for (int reg = 0; reg < 4; ++reg) {
            int il = wm * 64 + im * 16 + lhi * 4 + reg;
            int yi = yrl[il];
            int gi = i0 + il;
            for (int in = 0; in < 4; ++in) {
                int jl = wn * 64 + in * 16 + l16;
                float s  = acc[im][in][reg];
                float sT = s * INV_T;
                float e  = __expf(sT);
                float l  = __logf(e + EPS_C);
                float term = (yi == ycl[jl]) ? (sT - l) : (LOG_EPS - l);
                if (gi != (j0 + jl)) local += term;
            }
        }
    }
    for (int m = 1; m < 64; m <<= 1) local += __shfl_xor(local, m);
    if (lane == 0) wsum[w] = local;
    __syncthreads();
    if (tid == 0)
        partials[blockIdx.y * gridDim.x + blockIdx.x] =
            ((double)wsum[0] + (double)wsum[1]) + ((double)wsum[2] + (double)wsum[3]);
}

// ---------------------------------------------------------------------------
__global__ __launch_bounds__(256) void finalize_kernel(
    const double* __restrict__ partials, float* __restrict__ out)
{
    __shared__ double sh[4];
    double loc = 0.0;
    for (int i = threadIdx.x; i < 4096; i += 256) loc += partials[i];
    for (int m = 1; m < 64; m <<= 1) loc += __shfl_xor(loc, m);
    int lane = threadIdx.x & 63, w = threadIdx.x >> 6;
    if (lane == 0) sh[w] = loc;
    __syncthreads();
    if (threadIdx.x == 0)
        out[0] = (float)(-(sh[0] + sh[1] + sh[2] + sh[3]) / (double)B_TOT);
}

// ---------------------------------------------------------------------------
extern "C" void kernel_launch(void* const* d_in, const int* in_sizes, int n_in,
                              void* d_out, int out_size, void* d_ws, size_t ws_size,
                              hipStream_t stream)
{
    // ws layout: [partials 32KB | pad->64KB | fs 2MB | ft 2MB | Ws16 512KB | Wt16 512KB]
    const size_t WS_NEEDED = (64 << 10) + (4 << 20) + (1 << 20);
    if (ws_size < WS_NEEDED) return;   // readable failure instead of OOB fault

    const float* f_s = (const float*)d_in[0];
    const float* f_t = (const float*)d_in[1];
    const int*   y   = (const int*)d_in[2];
    const float* W_s = (const float*)d_in[3];
    const float* b_s = (const float*)d_in[4];
    const float* W_t = (const float*)d_in[5];
    const float* b_t = (const float*)d_in[6];
    float* out = (float*)d_out;

    char* ws = (char*)d_ws;
    double* partials = (double*)ws;                               // 32 KB
    half_t* fs   = (half_t*)(ws + (64 << 10));                    // 2 MB
    half_t* ft   = (half_t*)(ws + (64 << 10) + (2 << 20));        // 2 MB
    half_t* Ws16 = (half_t*)(ws + (64 << 10) + (4 << 20));        // 512 KB
    half_t* Wt16 = (half_t*)(ws + (64 << 10) + (4 << 20) + (512 << 10));

    cvt_w_kernel<<<dim3(256, 2), 256, 0, stream>>>(W_s, W_t, Ws16, Wt16);
    embed_kernel<<<dim3(256, 2), 256, 0, stream>>>(f_s, f_t, Ws16, Wt16, b_s, b_t, fs, ft);
    loss_kernel<<<dim3(64, 64), 256, 0, stream>>>(fs, ft, y, partials);
    finalize_kernel<<<1, 256, 0, stream>>>(partials, out);
    (void)in_sizes; (void)n_in; (void)out_size;
}

// Round 3
// 207.893 us; speedup vs baseline: 1.3714x; 1.0303x over previous
//
#include <hip/hip_runtime.h>
#include <math.h>

// CRDLoss on MI355X.
// Phase 0: convert W_s/W_t -> fp16 in ws (1 MB, L2-resident thereafter).
// Phase 1: embed (GEMM 8192x2048x128 + bias + L2 norm) -> fp16 embeddings.
//          R9 structure: BK=128, double-buffered 80KB LDS, XOR-swizzled,
//          B via global_load_lds w=16, A reg-staged 2 ahead, counted vmcnt.
// Phase 2: 8192x8192 similarity via f16 MFMA. R10: epilogue reduced to
//          sum{log2(2^u+eps)} + masked sum{u} in log2 domain (6 VALU + 2
//          trans per element, was ~13+2).  Pos/neg split moved to finalize
//          via y-histogram:  Sum = ln2*(SumU - SumL) + N_neg*ln(eps).
// Phase 3: finalize: reduce partials + y histogram -> N_pos/N_neg -> loss.

typedef _Float16 half_t;
typedef half_t halfx4 __attribute__((ext_vector_type(4)));
typedef half_t halfx8 __attribute__((ext_vector_type(8)));
typedef float f32x4 __attribute__((ext_vector_type(4)));

#define B_TOT   8192
#define K_EMB   2048
#define F_DIM   128
#define INV_T   14.285714285714286f   // 1/0.07
#define EPS_C   0.97f
#define CU_L2   20.60992915555662f    // (1/T) * log2(e)
#define LN2_D   0.6931471805599453
#define LNEPS_D (-0.030459207484708574)  // ln(0.97), double

// hardware transcendentals (2^x, log2 x) without range-conversion muls
__device__ __forceinline__ float fexp2(float x) {
#if __has_builtin(__builtin_amdgcn_exp2f)
    return __builtin_amdgcn_exp2f(x);
#else
    return __expf(x * 0.6931471805599453f);
#endif
}
__device__ __forceinline__ float flog2(float x) {
#if __has_builtin(__builtin_amdgcn_logf)
    return __builtin_amdgcn_logf(x);
#else
    return __logf(x) * 1.4426950408889634f;
#endif
}

// ---------------------------------------------------------------------------
// W fp32 -> fp16.  grid = (256, 2); block = 256; one float4 per thread.
// ---------------------------------------------------------------------------
__global__ __launch_bounds__(256) void cvt_w_kernel(
    const float* __restrict__ Ws, const float* __restrict__ Wt,
    half_t* __restrict__ Ws16, half_t* __restrict__ Wt16)
{
    const float* src = blockIdx.y ? Wt : Ws;
    half_t* dst = blockIdx.y ? Wt16 : Ws16;
    int pos4 = blockIdx.x * 256 + threadIdx.x;      // 0..65535
    float4 v = *(const float4*)(src + (size_t)pos4 * 4);
    halfx4 h4 = {(half_t)v.x, (half_t)v.y, (half_t)v.z, (half_t)v.w};
    *(halfx4*)(dst + (size_t)pos4 * 4) = h4;
}

// ---------------------------------------------------------------------------
// Embed helpers
// ---------------------------------------------------------------------------
__device__ __forceinline__ void cvst(uint4* dst, float4 x, float4 y)
{
    halfx8 h = {(half_t)x.x, (half_t)x.y, (half_t)x.z, (half_t)x.w,
                (half_t)y.x, (half_t)y.y, (half_t)y.z, (half_t)y.w};
    *(halfx8*)dst = h;
}

__device__ __forceinline__ void gload_lds16(const void* g, void* l)
{
    __builtin_amdgcn_global_load_lds(
        (const __attribute__((address_space(1))) void*)g,
        (__attribute__((address_space(3))) void*)l,
        16, 0, 0);
}

// ---------------------------------------------------------------------------
// Embed: 32-row tile x all 128 cols, BK=128 (16 k-tiles).  (unchanged R9)
// grid = (256, 2); block = 256 (4 waves: wm=w&1 row-halves, wn=w>>1 col-halves).
// LDS (uint4 units): [As0 512][As1 512][Bs0 2048][Bs1 2048] = 80 KB -> 2 blk/CU.
// ---------------------------------------------------------------------------
__global__ __launch_bounds__(256) void embed_kernel(
    const float* __restrict__ Xs, const float* __restrict__ Xt,
    const half_t* __restrict__ Ws16, const half_t* __restrict__ Wt16,
    const float* __restrict__ bs, const float* __restrict__ bt,
    half_t* __restrict__ outs, half_t* __restrict__ outt)
{
    const float* X; const half_t* W16; const float* bias; half_t* out;
    if (blockIdx.y == 0) { X = Xs; W16 = Ws16; bias = bs; out = outs; }
    else                 { X = Xt; W16 = Wt16; bias = bt; out = outt; }

    __shared__ uint4 smem[5120];   // exactly 80 KB

    const int tid  = threadIdx.x;
    const int r0   = blockIdx.x * 32;
    const int lane = tid & 63;
    const int w    = tid >> 6;
    const int wm   = w & 1, wn = w >> 1;     // rows 16*wm, cols 64*wn
    const int l16  = lane & 15, lhi = lane >> 4;

    float bv[4];
#pragma unroll
    for (int in = 0; in < 4; ++in) bv[in] = bias[wn * 64 + in * 16 + l16];

    const int ar0 = tid >> 4;                 // 0..15 (rows ar0, ar0+16)
    const int ac  = tid & 15;                 // source slot
    const int axz = ac ^ ar0;                 // swizzled slot
    const float* aptr0 = X + (size_t)(r0 + ar0) * K_EMB + ac * 8;
    const float* aptr1 = aptr0 + (size_t)16 * K_EMB;

    const half_t* bgp[8];
#pragma unroll
    for (int i = 0; i < 8; ++i) {
        int rl = w * 32 + i * 4 + (lane >> 4);
        bgp[i] = W16 + (size_t)rl * K_EMB + (size_t)(((lane & 15) ^ (rl & 15)) * 8);
    }

    f32x4 acc[4];
#pragma unroll
    for (int in = 0; in < 4; ++in) acc[in] = f32x4{0.f, 0.f, 0.f, 0.f};

    float4 aR[4];

#define LOADA(T) do {                                                          \
        aR[0] = *(const float4*)(aptr0 + (size_t)(T) * 128);                   \
        aR[1] = *(const float4*)(aptr0 + (size_t)(T) * 128 + 4);               \
        aR[2] = *(const float4*)(aptr1 + (size_t)(T) * 128);                   \
        aR[3] = *(const float4*)(aptr1 + (size_t)(T) * 128 + 4);               \
    } while (0)

#define CVTA(BUF) do {                                                         \
        cvst(&smem[(BUF) * 512 + ar0 * 16 + axz], aR[0], aR[1]);               \
        cvst(&smem[(BUF) * 512 + ar0 * 16 + 256 + axz], aR[2], aR[3]);         \
    } while (0)

#define BGLL(BUF, T) do {                                                      \
        _Pragma("unroll")                                                      \
        for (int i = 0; i < 8; ++i)                                            \
            gload_lds16(bgp[i] + (size_t)(T) * 128,                            \
                        &smem[1024 + (BUF) * 2048 + w * 512 + i * 64]);        \
    } while (0)

#define COMPUTE(BUF) do {                                                      \
        _Pragma("unroll")                                                      \
        for (int kk = 0; kk < 4; ++kk) {                                       \
            const int sl = (kk * 4 + lhi) ^ l16;                               \
            halfx8 afrag = *(const halfx8*)&smem[(BUF) * 512 +                 \
                                                 (wm * 16 + l16) * 16 + sl];   \
            _Pragma("unroll")                                                  \
            for (int in = 0; in < 4; ++in) {                                   \
                halfx8 bfrag = *(const halfx8*)&smem[1024 + (BUF) * 2048 +     \
                                     (wn * 64 + in * 16 + l16) * 16 + sl];     \
                acc[in] = __builtin_amdgcn_mfma_f32_16x16x32_f16(              \
                    afrag, bfrag, acc[in], 0, 0, 0);                           \
            }                                                                  \
        }                                                                      \
    } while (0)

    BGLL(0, 0);
    LOADA(0);
    CVTA(0);
    LOADA(1);
    BGLL(1, 1);
    asm volatile("s_waitcnt lgkmcnt(0)" ::: "memory");
    __builtin_amdgcn_s_barrier();

#pragma unroll 2
    for (int t = 0; t < 14; ++t) {
        const int buf = t & 1;
        COMPUTE(buf);
        CVTA(buf ^ 1);
        LOADA(t + 2);
        asm volatile("s_waitcnt vmcnt(4) lgkmcnt(0)" ::: "memory");
        __builtin_amdgcn_s_barrier();
        BGLL(buf, t + 2);
    }
    COMPUTE(0);
    CVTA(1);
    asm volatile("s_waitcnt vmcnt(0) lgkmcnt(0)" ::: "memory");
    __builtin_amdgcn_s_barrier();
    COMPUTE(1);

#undef LOADA
#undef CVTA
#undef BGLL
#undef COMPUTE

    float* redS = (float*)smem;          // [32][2]
    float* invS = ((float*)smem) + 64;   // [32]

    float hh[4][4];
    float psum[4];
#pragma unroll
    for (int reg = 0; reg < 4; ++reg) {
        float p = 0.f;
#pragma unroll
        for (int in = 0; in < 4; ++in) {
            float v = acc[in][reg] + bv[in];
            hh[in][reg] = v;
            p += v * v;
        }
        p += __shfl_xor(p, 1);
        p += __shfl_xor(p, 2);
        p += __shfl_xor(p, 4);
        p += __shfl_xor(p, 8);
        psum[reg] = p;
    }
    if (l16 == 0)
#pragma unroll
        for (int reg = 0; reg < 4; ++reg)
            redS[(wm * 16 + lhi * 4 + reg) * 2 + wn] = psum[reg];
    __syncthreads();
    if (tid < 32) invS[tid] = rsqrtf(redS[tid * 2] + redS[tid * 2 + 1]);
    __syncthreads();

#pragma unroll
    for (int in = 0; in < 4; ++in)
#pragma unroll
        for (int reg = 0; reg < 4; ++reg) {
            int row = wm * 16 + lhi * 4 + reg;
            int col = wn * 64 + in * 16 + l16;
            out[(size_t)(r0 + row) * F_DIM + col] = (half_t)(hh[in][reg] * invS[row]);
        }
}

// ---------------------------------------------------------------------------
// Loss: 128x128 tile of fs·ft^T, K=128 in two 64-wide LDS chunks (33 KB LDS).
// grid = (64, 64); block = 256.
// Epilogue (R10): per element u = s*(1/T)*log2e; accumulate
//   sumL += log2(2^u + eps)   over off-diagonal elements
//   sumU += u                 over positive (y_i==y_j) off-diagonal elements
// Block partial = sumU - sumL (both scale by ln2, applied in finalize).
// Diagonal predicate hoisted to block level (64/4096 blocks).
// ---------------------------------------------------------------------------
__global__ __launch_bounds__(256) void loss_kernel(
    const half_t* __restrict__ FS, const half_t* __restrict__ FT,
    const int* __restrict__ y, double* __restrict__ partials)
{
    __shared__ uint4 As4[128 * 8];   // 16 KB
    __shared__ uint4 Bs4[128 * 8];   // 16 KB
    __shared__ int   yrl[128], ycl[128];
    __shared__ float wsum[4];

    const int tid = threadIdx.x;
    const int i0  = blockIdx.x * 128;
    const int j0  = blockIdx.y * 128;

    if (tid < 128) yrl[tid] = y[i0 + tid];
    else           ycl[tid - 128] = y[j0 + tid - 128];

    const int lane = tid & 63;
    const int w    = tid >> 6;
    const int wm   = w >> 1, wn = w & 1;
    const int l16  = lane & 15, lhi = lane >> 4;

#pragma unroll
    for (int i = 0; i < 4; ++i) {
        int f = tid + i * 256;
        int row = f >> 3, c = f & 7;
        As4[row * 8 + (c ^ (row & 7))] = *(const uint4*)(FS + (size_t)(i0 + row) * F_DIM + c * 8);
    }
#pragma unroll
    for (int i = 0; i < 4; ++i) {
        int f = tid + i * 256;
        int row = f >> 3, c = f & 7;
        Bs4[row * 8 + (c ^ (row & 7))] = *(const uint4*)(FT + (size_t)(j0 + row) * F_DIM + c * 8);
    }
    __syncthreads();

    f32x4 acc[4][4];
    for (int im = 0; im < 4; ++im)
        for (int in = 0; in < 4; ++in)
            acc[im][in] = f32x4{0.f, 0.f, 0.f, 0.f};

    for (int kc = 0; kc < 2; ++kc) {
#pragma unroll
        for (int kk = 0; kk < 2; ++kk) {
            halfx8 a[4], b[4];
#pragma unroll
            for (int im = 0; im < 4; ++im) {
                int r = wm * 64 + im * 16 + l16;
                a[im] = *(const halfx8*)&As4[r * 8 + ((kk * 4 + lhi) ^ (r & 7))];
            }
#pragma unroll
            for (int in = 0; in < 4; ++in) {
                int r = wn * 64 + in * 16 + l16;
                b[in] = *(const halfx8*)&Bs4[r * 8 + ((kk * 4 + lhi) ^ (r & 7))];
            }
#pragma unroll
            for (int im = 0; im < 4; ++im)
#pragma unroll
                for (int in = 0; in < 4; ++in)
                    acc[im][in] = __builtin_amdgcn_mfma_f32_16x16x32_f16(
                        a[im], b[in], acc[im][in], 0, 0, 0);
        }
        if (kc == 0) {
            __syncthreads();
#pragma unroll
            for (int i = 0; i < 4; ++i) {
                int f = tid + i * 256;
                int row = f >> 3, c = f & 7;
                As4[row * 8 + (c ^ (row & 7))] =
                    *(const uint4*)(FS + (size_t)(i0 + row) * F_DIM + 64 + c * 8);
            }
#pragma unroll
            for (int i = 0; i < 4; ++i) {
                int f = tid + i * 256;
                int row = f >> 3, c = f & 7;
                Bs4[row * 8 + (c ^ (row & 7))] =
                    *(const uint4*)(FT + (size_t)(j0 + row) * F_DIM + 64 + c * 8);
            }
            __syncthreads();
        }
    }

    // y columns for this thread (4 LDS reads, hoisted)
    int yclv[4];
#pragma unroll
    for (int in = 0; in < 4; ++in) yclv[in] = ycl[wn * 64 + in * 16 + l16];

    float sumL = 0.f, sumU = 0.f;
    if (i0 != j0) {
        // clean path: 6 full-rate + 2 trans per element
#pragma unroll
        for (int im = 0; im < 4; ++im)
#pragma unroll
            for (int reg = 0; reg < 4; ++reg) {
                const int yi = yrl[wm * 64 + im * 16 + lhi * 4 + reg];
#pragma unroll
                for (int in = 0; in < 4; ++in) {
                    float u  = acc[im][in][reg] * CU_L2;
                    float e  = fexp2(u);
                    float l2 = flog2(e + EPS_C);
                    sumL += l2;
                    sumU += (yi == yclv[in]) ? u : 0.f;
                }
            }
    } else {
        // diagonal block: exclude il == jl
#pragma unroll
        for (int im = 0; im < 4; ++im)
#pragma unroll
            for (int reg = 0; reg < 4; ++reg) {
                const int il = wm * 64 + im * 16 + lhi * 4 + reg;
                const int yi = yrl[il];
#pragma unroll
                for (int in = 0; in < 4; ++in) {
                    const int jl = wn * 64 + in * 16 + l16;
                    float u  = acc[im][in][reg] * CU_L2;
                    float e  = fexp2(u);
                    float l2 = flog2(e + EPS_C);
                    bool off = (il != jl);
                    sumL += off ? l2 : 0.f;
                    sumU += (off && yi == yclv[in]) ? u : 0.f;
                }
            }
    }

    float local = sumU - sumL;
    for (int m = 1; m < 64; m <<= 1) local += __shfl_xor(local, m);
    if (lane == 0) wsum[w] = local;
    __syncthreads();
    if (tid == 0)
        partials[blockIdx.y * gridDim.x + blockIdx.x] =
            ((double)wsum[0] + (double)wsum[1]) + ((double)wsum[2] + (double)wsum[3]);
}

// ---------------------------------------------------------------------------
// Finalize: sum partials; y histogram -> N_pos/N_neg;
// loss = -( ln2 * sum + N_neg * ln(eps) ) / B
// ---------------------------------------------------------------------------
__global__ __launch_bounds__(256) void finalize_kernel(
    const double* __restrict__ partials, const int* __restrict__ y,
    float* __restrict__ out)
{
    __shared__ double sh[4];
    __shared__ int hist[128];
    if (threadIdx.x < 128) hist[threadIdx.x] = 0;
    __syncthreads();
    for (int i = threadIdx.x; i < B_TOT; i += 256) atomicAdd(&hist[y[i]], 1);

    double loc = 0.0;
    for (int i = threadIdx.x; i < 4096; i += 256) loc += partials[i];
    for (int m = 1; m < 64; m <<= 1) loc += __shfl_xor(loc, m);
    int lane = threadIdx.x & 63, w = threadIdx.x >> 6;
    if (lane == 0) sh[w] = loc;
    __syncthreads();
    if (threadIdx.x == 0) {
        long long npos = 0;
        for (int c = 0; c < 128; ++c) {
            long long n = hist[c];
            npos += n * n;
        }
        npos -= B_TOT;   // remove diagonal (y_i == y_i)
        long long nneg = (long long)B_TOT * (B_TOT - 1) - npos;
        double total = (sh[0] + sh[1]) + (sh[2] + sh[3]);
        out[0] = (float)(-(LN2_D * total + (double)nneg * LNEPS_D) / (double)B_TOT);
    }
}

// ---------------------------------------------------------------------------
extern "C" void kernel_launch(void* const* d_in, const int* in_sizes, int n_in,
                              void* d_out, int out_size, void* d_ws, size_t ws_size,
                              hipStream_t stream)
{
    // ws layout: [partials 32KB | pad->64KB | fs 2MB | ft 2MB | Ws16 512KB | Wt16 512KB]
    const size_t WS_NEEDED = (64 << 10) + (4 << 20) + (1 << 20);
    if (ws_size < WS_NEEDED) return;   // readable failure instead of OOB fault

    const float* f_s = (const float*)d_in[0];
    const float* f_t = (const float*)d_in[1];
    const int*   y   = (const int*)d_in[2];
    const float* W_s = (const float*)d_in[3];
    const float* b_s = (const float*)d_in[4];
    const float* W_t = (const float*)d_in[5];
    const float* b_t = (const float*)d_in[6];
    float* out = (float*)d_out;

    char* ws = (char*)d_ws;
    double* partials = (double*)ws;                               // 32 KB
    half_t* fs   = (half_t*)(ws + (64 << 10));                    // 2 MB
    half_t* ft   = (half_t*)(ws + (64 << 10) + (2 << 20));        // 2 MB
    half_t* Ws16 = (half_t*)(ws + (64 << 10) + (4 << 20));        // 512 KB
    half_t* Wt16 = (half_t*)(ws + (64 << 10) + (4 << 20) + (512 << 10));

    cvt_w_kernel<<<dim3(256, 2), 256, 0, stream>>>(W_s, W_t, Ws16, Wt16);
    embed_kernel<<<dim3(256, 2), 256, 0, stream>>>(f_s, f_t, Ws16, Wt16, b_s, b_t, fs, ft);
    loss_kernel<<<dim3(64, 64), 256, 0, stream>>>(fs, ft, y, partials);
    finalize_kernel<<<1, 256, 0, stream>>>(partials, y, out);
    (void)in_sizes; (void)n_in; (void)out_size;
}